// Round 5
// baseline (519.472 us; speedup 1.0000x reference)
//
#include <hip/hip_runtime.h>
#include <hip/hip_bf16.h>

typedef __attribute__((ext_vector_type(8))) short bf16x8;
typedef __attribute__((ext_vector_type(4))) float f32x4;
typedef __attribute__((ext_vector_type(4))) int   i32x4;
typedef __attribute__((ext_vector_type(4))) unsigned short u16x4;
typedef unsigned short u16;

#define G_ 20000
#define B_ 512
#define NBLK 256

__device__ __forceinline__ u16 f2bf(float x) {
  __hip_bfloat16 h = __float2bfloat16(x);   // RTN
  return __builtin_bit_cast(u16, h);
}

__device__ __forceinline__ void glds16(const void* g, void* l) {
  __builtin_amdgcn_global_load_lds(
      (const __attribute__((address_space(1))) void*)g,
      (__attribute__((address_space(3))) void*)l, 16, 0, 0);
}

// swizzled u16 index for logical (row b, col kk in [0,64)) within a slab:
// 16-B chunk c stored at c ^ (b&7)
__device__ __forceinline__ int swz(int b, int kk) {
  return b * 64 + ((((kk >> 3) & 7) ^ (b & 7)) << 3) + (kk & 7);
}

// zero the grid-barrier counters (runs before mega-kernel in the same graph)
__global__ void k_zero(unsigned* cnt) {
  if (threadIdx.x < 16) cnt[threadIdx.x] = 0;
}

// device-scope grid barrier; all NBLK blocks participate in every barrier
__device__ __forceinline__ void gridbar(unsigned* cnt, int j) {
  __syncthreads();
  if (threadIdx.x == 0) {
    __threadfence();                       // release: prior writes visible
    atomicAdd(&cnt[j], 1u);
    while (atomicAdd(&cnt[j], 0u) < NBLK) __builtin_amdgcn_s_sleep(8);
    __threadfence();                       // acquire: invalidate stale caches
  }
  __syncthreads();
}

// ---------------------------------------------------------------------------
// GEMM phase: part[split] = A(512 x 64k bf16, swizzled slabs) @ W(fp32->bf16)
// BM=512 BN=128 BK=64; 8 waves 4x2 (wave-tile 128x64); single-buffered As via
// global_load_lds; W reg-prefetched one slab ahead; counted vmcnt.
// ---------------------------------------------------------------------------
__device__ void gemm128(const u16* __restrict__ At, const float* __restrict__ W,
                        float* __restrict__ part, u16* As, u16* Bs,
                        int nSlabs, int S, int split, int nt,
                        int Kvalid, int Nvalid, int Npad) {
  const int tid = threadIdx.x, lane = tid & 63, wv = tid >> 6;
  const int wr = wv >> 1, wc = wv & 1, l15 = lane & 15, l4 = lane >> 4;
  const int bn = tid & 127, bh = tid >> 7;          // W staging: col, k-quarter
  const int n0 = nt * 128, nW = n0 + bn;
  const bool nok = nW < Nvalid;
  const int s0 = (int)(((long)split * nSlabs) / S);
  const int s1 = (int)(((long)(split + 1) * nSlabs) / S);
  const int sLast = s1 - 1;

  f32x4 acc[8][4];
  #pragma unroll
  for (int i = 0; i < 8; ++i)
    #pragma unroll
    for (int j = 0; j < 4; ++j) acc[i][j] = f32x4{0.f, 0.f, 0.f, 0.f};

  float wreg[16];

  auto GLDS = [&](int s) {
    const char* sb = (const char*)(At + (size_t)s * 32768);
    char* lb = (char*)As;
    #pragma unroll
    for (int j = 0; j < 8; ++j) {
      int q = wv * 8 + j;                           // 1-KB chunk, wave-uniform
      glds16(sb + q * 1024 + lane * 16, lb + q * 1024);
    }
  };
  auto WLOAD = [&](int s) {
    int kb = s * 64 + bh * 16;
    #pragma unroll
    for (int j = 0; j < 16; ++j) {
      int k = kb + j;
      wreg[j] = (nok && k < Kvalid) ? W[(size_t)k * Nvalid + nW] : 0.f;
    }
  };
  auto BSTORE = [&]() {
    #pragma unroll
    for (int h = 0; h < 2; ++h) {
      i32x4 pk;
      #pragma unroll
      for (int q = 0; q < 4; ++q) {
        u16 lo = f2bf(wreg[h * 8 + q * 2]);
        u16 hi = f2bf(wreg[h * 8 + q * 2 + 1]);
        pk[q] = (int)(unsigned)lo | ((int)(unsigned)hi << 16);
      }
      int cch = bh * 2 + h;
      *(i32x4*)&Bs[bn * 64 + ((cch ^ (bn & 7)) << 3)] = pk;
    }
  };
  auto COMPUTE = [&]() {
    #pragma unroll
    for (int kk = 0; kk < 2; ++kk) {
      bf16x8 bfr[4];
      #pragma unroll
      for (int nf = 0; nf < 4; ++nf) {
        int n = wc * 64 + nf * 16 + l15;
        int cch = kk * 4 + l4;
        bfr[nf] = *(const bf16x8*)&Bs[n * 64 + ((cch ^ (n & 7)) << 3)];
      }
      #pragma unroll
      for (int mf = 0; mf < 8; ++mf) {
        int m = wr * 128 + mf * 16 + l15;
        int cch = kk * 4 + l4;
        bf16x8 af = *(const bf16x8*)&As[m * 64 + ((cch ^ (m & 7)) << 3)];
        #pragma unroll
        for (int nf = 0; nf < 4; ++nf)
          acc[mf][nf] = __builtin_amdgcn_mfma_f32_16x16x32_bf16(af, bfr[nf], acc[mf][nf], 0, 0, 0);
      }
    }
  };

  // prologue: Bs(s0) + As(s0); W(s0+1) left in flight
  WLOAD(s0);
  BSTORE();                                 // waits W(s0) only
  GLDS(s0);                                 // 8 glds in flight
  WLOAD((s0 + 1 > sLast) ? sLast : s0 + 1); // 16 more in flight
  asm volatile("s_waitcnt vmcnt(16) lgkmcnt(0)" ::: "memory");  // retire glds
  __builtin_amdgcn_s_barrier();

  for (int s = s0; s < s1; ++s) {
    COMPUTE();                              // W(s+1) streams underneath
    __builtin_amdgcn_s_barrier();
    if (s < sLast) {
      BSTORE();                             // wreg = W(s+1), already landed
      GLDS(s + 1);                          // [G8]
      WLOAD((s + 2 > sLast) ? sLast : s + 2);  // [G8, W16]
      asm volatile("s_waitcnt vmcnt(16) lgkmcnt(0)" ::: "memory"); // retire G8
      __builtin_amdgcn_s_barrier();
    }
  }

  float* outp = part + (size_t)split * B_ * Npad;
  #pragma unroll
  for (int mf = 0; mf < 8; ++mf)
    #pragma unroll
    for (int nf = 0; nf < 4; ++nf) {
      int col = n0 + wc * 64 + nf * 16 + l15;
      int rb = wr * 128 + mf * 16 + l4 * 4;
      #pragma unroll
      for (int r = 0; r < 4; ++r)
        outp[(size_t)(rb + r) * Npad + col] = acc[mf][nf][r];
    }
}

// ---------------------------------------------------------------------------
// Persistent mega-kernel: all phases, software grid barriers between.
// ---------------------------------------------------------------------------
__global__ __launch_bounds__(512, 2) void k_mega(
    const float* __restrict__ expr, const int* __restrict__ cc,
    const float* __restrict__ cnc,
    const float* __restrict__ bw1, const float* __restrict__ bb1,
    const float* __restrict__ bw2, const float* __restrict__ bb2,
    const float* __restrict__ gw,  const float* __restrict__ gb,
    const float* __restrict__ race, const float* __restrict__ eth,
    const float* __restrict__ inter, const float* __restrict__ prot,
    const float* __restrict__ mw, const float* __restrict__ mb,
    const float* __restrict__ w0, const float* __restrict__ bias0,
    const float* __restrict__ w1, const float* __restrict__ bias1,
    const float* __restrict__ w2, const float* __restrict__ bias2,
    const float* __restrict__ w3, const float* __restrict__ bias3,
    const float* __restrict__ w4, const float* __restrict__ bias4,
    u16* __restrict__ Xt, u16* __restrict__ H1t, u16* __restrict__ H2t,
    float* __restrict__ part, unsigned* __restrict__ cnt,
    float* __restrict__ out) {

  __shared__ __align__(16) u16 As[512 * 64];   // 64 KB
  __shared__ __align__(16) u16 Bs[128 * 64];   // 16 KB

  const int tid = threadIdx.x, bid = blockIdx.x;

  // ---- P0: gene micro-MLP + clinical -> swizzled X slabs -------------------
  for (int w = bid; w < 656; w += NBLK) {
    if (w < 640) {
      int gc = w >> 4, bt = w & 15, bb = bt * 32;
      int g = gc * 512 + tid;
      if (g < G_) {
        f32x4 w1a = ((const f32x4*)bw1)[g];
        f32x4 w1b = ((const f32x4*)bw1)[G_ + g];
        f32x4 b1a = ((const f32x4*)bb1)[g];
        f32x4 b1b = ((const f32x4*)bb1)[G_ + g];
        f32x4 w2a = ((const f32x4*)bw2)[g];
        f32x4 w2b = ((const f32x4*)bw2)[G_ + g];
        float bb2a = bb2[g], bb2b = bb2[G_ + g];
        float gw0 = gw[g * 2], gw1 = gw[g * 2 + 1];
        float gbg = gb[g];
        u16* slab = Xt + (size_t)(g >> 6) * 32768;
        int kk = g & 63, ch = (kk >> 3) & 7, klo = kk & 7;
        #pragma unroll 4
        for (int b = bb; b < bb + 32; ++b) {
          float x0 = expr[(size_t)(b * 2) * G_ + g];
          float x1 = expr[(size_t)(b * 2 + 1) * G_ + g];
          float h0 = fmaxf(x0 * w1a.x + b1a.x, 0.f);
          float h1 = fmaxf(x0 * w1a.y + b1a.y, 0.f);
          float h2 = fmaxf(x0 * w1a.z + b1a.z, 0.f);
          float h3 = fmaxf(x0 * w1a.w + b1a.w, 0.f);
          float s0 = fmaxf(h0 * w2a.x + h1 * w2a.y + h2 * w2a.z + h3 * w2a.w + bb2a, 0.f);
          float g0 = fmaxf(x1 * w1b.x + b1b.x, 0.f);
          float g1 = fmaxf(x1 * w1b.y + b1b.y, 0.f);
          float g2 = fmaxf(x1 * w1b.z + b1b.z, 0.f);
          float g3 = fmaxf(x1 * w1b.w + b1b.w, 0.f);
          float s1 = fmaxf(g0 * w2b.x + g1 * w2b.y + g2 * w2b.z + g3 * w2b.w + bb2b, 0.f);
          float e = fmaxf(s0 * gw0 + s1 * gw1 + gbg, 0.f);
          slab[b * 64 + ((ch ^ (b & 7)) << 3) + klo] = f2bf(e);
        }
      }
    } else {
      int bt = w - 640;
      int b = bt * 32 + (tid >> 4);
      int j0 = (tid & 15) * 6;
      int c0 = cc[b * 3], c1 = cc[b * 3 + 1], c2 = cc[b * 3 + 2];
      float nc[10];
      #pragma unroll
      for (int v = 0; v < 10; ++v)
        nc[v] = fmaxf(cnc[b * 20 + v] * mw[v * 2] + cnc[b * 20 + 10 + v] * mw[v * 2 + 1] + mb[v], 0.f);
      #pragma unroll
      for (int jj = 0; jj < 6; ++jj) {
        int j = j0 + jj;
        float v;
        if (j < 8)       v = race[c0 * 8 + j];
        else if (j < 12) v = eth[c1 * 4 + (j - 8)];
        else if (j < 20) v = inter[(c0 * 4 + c1) * 8 + (j - 12)];
        else if (j < 28) v = prot[c2 * 8 + (j - 20)];
        else if (j < 38) v = nc[j - 28];
        else             v = 0.f;
        int k = 20000 + j;
        Xt[(size_t)(k >> 6) * 32768 + swz(b, k & 63)] = f2bf(v);
      }
    }
  }
  gridbar(cnt, 0);

  // ---- P1: L0 (512x20038)@(20038x5009), nt=40 x S=6 = 240 blocks -----------
  if (bid < 240)
    gemm128(Xt, w0, part, As, Bs, 314, 6, bid / 40, bid % 40, 20038, 5009, 5120);
  gridbar(cnt, 1);

  // ---- P2: reduce L0 partials (+bias+relu) -> H1t (80 slabs) ---------------
  for (int u = bid * 512 + tid; u < 655360; u += NBLK * 512) {
    int b = u / 1280, n = (u - b * 1280) * 4;
    float v[4] = {0.f, 0.f, 0.f, 0.f};
    #pragma unroll
    for (int s = 0; s < 6; ++s) {
      f32x4 p = *(const f32x4*)&part[(size_t)s * B_ * 5120 + (size_t)b * 5120 + n];
      v[0] += p[0]; v[1] += p[1]; v[2] += p[2]; v[3] += p[3];
    }
    u16x4 o;
    #pragma unroll
    for (int r = 0; r < 4; ++r) {
      float bi = (n + r < 5009) ? bias0[n + r] : 0.f;
      o[r] = f2bf(fmaxf(v[r] + bi, 0.f));
    }
    *(u16x4*)&H1t[(size_t)(n >> 6) * 32768 + swz(b, n & 63)] = o;
  }
  gridbar(cnt, 2);

  // ---- P3: L1 (512x5009)@(5009x1252), nt=10 x S=8 = 80 blocks --------------
  if (bid < 80)
    gemm128(H1t, w1, part, As, Bs, 80, 8, bid / 10, bid % 10, 5009, 1252, 1280);
  gridbar(cnt, 3);

  // ---- P4: reduce L1 -> H2t (20 slabs) -------------------------------------
  for (int u = bid * 512 + tid; u < 163840; u += NBLK * 512) {
    int b = u / 320, n = (u - b * 320) * 4;
    float v[4] = {0.f, 0.f, 0.f, 0.f};
    #pragma unroll
    for (int s = 0; s < 8; ++s) {
      f32x4 p = *(const f32x4*)&part[(size_t)s * B_ * 1280 + (size_t)b * 1280 + n];
      v[0] += p[0]; v[1] += p[1]; v[2] += p[2]; v[3] += p[3];
    }
    u16x4 o;
    #pragma unroll
    for (int r = 0; r < 4; ++r) {
      float bi = (n + r < 1252) ? bias1[n + r] : 0.f;
      o[r] = f2bf(fmaxf(v[r] + bi, 0.f));
    }
    *(u16x4*)&H2t[(size_t)(n >> 6) * 32768 + swz(b, n & 63)] = o;
  }
  gridbar(cnt, 4);

  // ---- P5: L2 (512x1252)@(1252x313), nt=3 x S=5 = 15 blocks ----------------
  if (bid < 15)
    gemm128(H2t, w2, part, As, Bs, 20, 5, bid / 3, bid % 3, 1252, 313, 384);
  gridbar(cnt, 5);

  // ---- P6: fused reduce(L2)+bias+relu -> L3 -> L4, 2 rows per block --------
  float* h3 = (float*)As;        // 320 floats
  float* h4 = h3 + 320;          // 78 floats
  #pragma unroll
  for (int rep = 0; rep < 2; ++rep) {
    int r = bid * 2 + rep;
    if (tid < 320) {
      float v = 0.f;
      #pragma unroll
      for (int s = 0; s < 5; ++s)
        v += part[(size_t)s * B_ * 384 + (size_t)r * 384 + tid];
      float bi = (tid < 313) ? bias2[tid] : 0.f;
      h3[tid] = fmaxf(v + bi, 0.f);
    }
    __syncthreads();
    if (tid < 78) {
      float a = bias3[tid];
      #pragma unroll 4
      for (int k = 0; k < 313; ++k) a += h3[k] * w3[k * 78 + tid];
      h4[tid] = fmaxf(a, 0.f);
    }
    __syncthreads();
    if (tid < 2) {
      float a = bias4[tid];
      for (int k = 0; k < 78; ++k) a += h4[k] * w4[k * 2 + tid];
      out[r * 2 + tid] = a;
    }
    __syncthreads();
  }
}

// ---------------------------------------------------------------------------
extern "C" void kernel_launch(void* const* d_in, const int* in_sizes, int n_in,
                              void* d_out, int out_size, void* d_ws, size_t ws_size,
                              hipStream_t stream) {
  const float* expr = (const float*)d_in[0];
  const int*   cc   = (const int*)d_in[1];
  const float* cnc  = (const float*)d_in[2];
  const float* bw1  = (const float*)d_in[3];
  const float* bb1  = (const float*)d_in[4];
  const float* bw2  = (const float*)d_in[5];
  const float* bb2  = (const float*)d_in[6];
  const float* gw   = (const float*)d_in[7];
  const float* gb   = (const float*)d_in[8];
  const float* race = (const float*)d_in[9];
  const float* eth  = (const float*)d_in[10];
  const float* inter= (const float*)d_in[11];
  const float* prot = (const float*)d_in[12];
  const float* mw   = (const float*)d_in[13];
  const float* mb   = (const float*)d_in[14];
  const float* w0 = (const float*)d_in[15]; const float* b0 = (const float*)d_in[16];
  const float* w1 = (const float*)d_in[17]; const float* b1 = (const float*)d_in[18];
  const float* w2 = (const float*)d_in[19]; const float* b2 = (const float*)d_in[20];
  const float* w3 = (const float*)d_in[21]; const float* b3 = (const float*)d_in[22];
  const float* w4 = (const float*)d_in[23]; const float* b4 = (const float*)d_in[24];

  // workspace: Xt 314 slabs | H1t 80 | H2t 20 | part (63 MB) | cnt @ 96 MB
  u16* Xt  = (u16*)d_ws;
  u16* H1t = Xt  + (size_t)314 * 32768;
  u16* H2t = H1t + (size_t)80 * 32768;
  float* part = (float*)(H2t + (size_t)20 * 32768);
  unsigned* cnt = (unsigned*)((char*)d_ws + (size_t)96 * 1024 * 1024);

  k_zero<<<1, 64, 0, stream>>>(cnt);
  k_mega<<<NBLK, 512, 0, stream>>>(expr, cc, cnc, bw1, bb1, bw2, bb2, gw, gb,
                                   race, eth, inter, prot, mw, mb,
                                   w0, b0, w1, b1, w2, b2, w3, b3, w4, b4,
                                   Xt, H1t, H2t, part, cnt, (float*)d_out);
}